// Round 8
// baseline (184.741 us; speedup 1.0000x reference)
//
#include <hip/hip_runtime.h>
#include <hip/hip_bf16.h>
#include <cstdint>

#define NB   64
#define CIN  1024
#define HWSP 196
#define MTOT 12544
#define PL   256
#define COUT 1024

using f32x4 = __attribute__((ext_vector_type(4))) float;
using s16x8 = __attribute__((ext_vector_type(8))) short;

static __device__ __forceinline__ short f2bf(float f) {
  union { __hip_bfloat16 h; short s; } u;
  u.h = __float2bfloat16(f);
  return u.s;
}
static __device__ __forceinline__ float bf2f(short s) {
  union { float f; unsigned u; } x;
  x.u = ((unsigned)(unsigned short)s) << 16;
  return x.f;
}

static __device__ __forceinline__ void gload16(const void* g, void* l) {
  __builtin_amdgcn_global_load_lds((const __attribute__((address_space(1))) void*)g,
                                   (__attribute__((address_space(3))) void*)l, 16, 0, 0);
}

// ------------- merged prep: x-transpose | weight cast/reorder | stats zero ---
__global__ __launch_bounds__(256) void k_prep(const float* __restrict__ x,
                                              const float* __restrict__ w1,
                                              const float* __restrict__ w2,
                                              const float* __restrict__ w3,
                                              short* __restrict__ xb,
                                              short* __restrict__ w1b,
                                              short* __restrict__ w2b,
                                              short* __restrict__ w3b,
                                              float* __restrict__ statszero) {
  const int bid = blockIdx.x;
  if (bid < 2048) {
    __shared__ float tile[32][197];
    const int n = bid >> 5;
    const int c0 = (bid & 31) * 32;
    for (int idx = threadIdx.x; idx < 32 * 196; idx += 256) {
      int cl = idx / 196, hw = idx % 196;
      tile[cl][hw] = x[((size_t)(n * CIN + c0 + cl)) * HWSP + hw];
    }
    __syncthreads();
    for (int idx = threadIdx.x; idx < 196 * 32; idx += 256) {
      int hw = idx >> 5, cl = idx & 31;
      xb[((size_t)(n * HWSP + hw)) * CIN + c0 + cl] = f2bf(tile[cl][hw]);
    }
  } else if (bid < 6400) {
    int i = (bid - 2048) * 256 + threadIdx.x;
    if (i < 262144) w1b[i] = f2bf(w1[i]);
    int j = i - 262144;
    if (j >= 0 && j < 589824) {
      int co = j / 2304, rem = j % 2304;
      int d = rem >> 8, ci = rem & 255;
      w2b[j] = f2bf(w2[((size_t)(co * 256 + ci)) * 9 + d]);
    }
    int k = i - 851968;
    if (k >= 0 && k < 262144) w3b[k] = f2bf(w3[k]);
  } else {
    // zero: stats (3072 f32) + counters + zerobuf
    for (int k = threadIdx.x; k < 3200; k += 256) statszero[k] = 0.f;
  }
}

// ---------------- MFMA GEMM + fused bias/BN epilogue -------------------------
// Tile BMxBNx64; 4 waves (2x2), per-wave (BM/2)x(BN/2).
// 2-phase double-buffer (stage(next); compute(cur); __syncthreads()).
// LDS read swizzle: byte = row*128 + ((k16 ^ (row&7)) << 4); staging uses
// linear LDS dest + inverse-swizzled global source (rule #21).
// FUSE=1: BN stats from raw acc -> device-scope grid barrier (all blocks
//         co-resident: grid <= 3 blocks/CU * 256) -> finalize sc/sh in-block
//         (bias folded into mean) -> relu(bn(acc)) -> single bf16 store.
// FUSE=0: bias-add, bf16 store, stats atomics (k_final applies BN later).
static __device__ __forceinline__ int swz(int row, int k16) {
  return row * 128 + (((unsigned)(k16 ^ (row & 7))) << 4);
}

template <int MODE, int K, int BM, int BN, int FUSE>
__global__ __launch_bounds__(256) void gemm_kernel(const short* __restrict__ A,
                                                   const short* __restrict__ Bw,
                                                   const float* __restrict__ bias,
                                                   const float* __restrict__ gamma,
                                                   const float* __restrict__ beta,
                                                   short* __restrict__ Yb,
                                                   float* __restrict__ st,
                                                   unsigned* __restrict__ cnt,
                                                   int nblk, int Nc,
                                                   const short* __restrict__ zerobuf) {
  constexpr int MI = BM / 32;
  constexpr int NJ = BN / 32;
  constexpr int ABYTES = BM * 128;
  __shared__ __align__(16) char lds[2][BM * 128 + BN * 128];

  const int m0 = blockIdx.x * BM;
  const int n0 = blockIdx.y * BN;
  const int t = threadIdx.x;
  const int lane = t & 63, wid = t >> 6;
  const int wm = wid >> 1, wn = wid & 1;
  const int g = lane >> 4, r = lane & 15;
  constexpr int NKT = K >> 6;

  const short* aSrc[MI];
  int aN[MI], aH[MI], aW[MI], aCi[MI];
#pragma unroll
  for (int q = 0; q < MI; ++q) {
    int chunk = t + q * 256;
    int row = chunk >> 3;
    int k16s = (chunk & 7) ^ (row & 7);
    if (MODE == 0) {
      aSrc[q] = A + (size_t)(m0 + row) * K + k16s * 8;
    } else {
      int m = m0 + row;
      int n_ = m / 196;
      int hw = m - n_ * 196;
      aN[q] = n_;
      aH[q] = hw / 14;
      aW[q] = hw - aH[q] * 14;
      aCi[q] = k16s * 8;
    }
  }
  const short* bSrc[NJ];
#pragma unroll
  for (int q = 0; q < NJ; ++q) {
    int chunk = t + q * 256;
    int row = chunk >> 3;
    int k16s = (chunk & 7) ^ (row & 7);
    bSrc[q] = Bw + (size_t)(n0 + row) * K + k16s * 8;
  }

  auto stage = [&](int buf, int kt) {
    const int k0 = kt << 6;
    char* dA = &lds[buf][0];
    char* dB = &lds[buf][ABYTES];
#pragma unroll
    for (int q = 0; q < MI; ++q) {
      const short* s;
      if (MODE == 0) {
        s = aSrc[q] + k0;
      } else {
        int d = kt >> 2;
        int dh = d / 3, dw = d - dh * 3;
        int hh = aH[q] + dh - 1, ww = aW[q] + dw - 1;
        s = ((unsigned)hh < 14u && (unsigned)ww < 14u)
                ? A + ((size_t)(aN[q] * 196 + hh * 14 + ww)) * 256 + (k0 & 255) + aCi[q]
                : zerobuf;
      }
      gload16(s, dA + (t + q * 256) * 16);
    }
#pragma unroll
    for (int q = 0; q < NJ; ++q)
      gload16(bSrc[q] + k0, dB + (t + q * 256) * 16);
  };

  f32x4 acc[MI][NJ] = {};
  auto compute = [&](int buf) {
    char* baseA = &lds[buf][0];
    char* baseB = &lds[buf][ABYTES];
#pragma unroll
    for (int ks = 0; ks < 2; ++ks) {
      s16x8 af[MI], bfr[NJ];
#pragma unroll
      for (int i = 0; i < MI; ++i)
        af[i] = *(const s16x8*)(baseA + swz(wm * (BM / 2) + i * 16 + r, ks * 4 + g));
#pragma unroll
      for (int j = 0; j < NJ; ++j)
        bfr[j] = *(const s16x8*)(baseB + swz(wn * (BN / 2) + j * 16 + r, ks * 4 + g));
#pragma unroll
      for (int i = 0; i < MI; ++i)
#pragma unroll
        for (int j = 0; j < NJ; ++j)
          acc[i][j] = __builtin_amdgcn_mfma_f32_16x16x32_bf16(af[i], bfr[j], acc[i][j], 0, 0, 0);
    }
  };

  stage(0, 0);
  __syncthreads();
  int cur = 0;
#pragma unroll 1
  for (int kt = 0; kt < NKT - 1; ++kt) {
    stage(cur ^ 1, kt + 1);
    compute(cur);
    __syncthreads();
    cur ^= 1;
  }
  compute(cur);

  if (FUSE == 0) {
    // bias, bf16 store, per-channel sum/sumsq (incl. bias) -> atomics
#pragma unroll
    for (int j = 0; j < NJ; ++j) {
      int col = n0 + wn * (BN / 2) + j * 16 + r;
      float bv = bias[col];
      float ps = 0.f, pq = 0.f;
#pragma unroll
      for (int i = 0; i < MI; ++i) {
        int row_base = m0 + wm * (BM / 2) + i * 16 + g * 4;
#pragma unroll
        for (int rr = 0; rr < 4; ++rr) {
          float v = acc[i][j][rr] + bv;
          ps += v;
          pq += v * v;
          Yb[(size_t)(row_base + rr) * Nc + col] = f2bf(v);
        }
      }
      ps += __shfl_xor(ps, 16);
      ps += __shfl_xor(ps, 32);
      pq += __shfl_xor(pq, 16);
      pq += __shfl_xor(pq, 32);
      if (lane < 16) {
        atomicAdd(&st[col], ps);
        atomicAdd(&st[Nc + col], pq);
      }
    }
  } else {
    // stats from RAW acc (bias folded later into mean)
#pragma unroll
    for (int j = 0; j < NJ; ++j) {
      int col = n0 + wn * (BN / 2) + j * 16 + r;
      float ps = 0.f, pq = 0.f;
#pragma unroll
      for (int i = 0; i < MI; ++i)
#pragma unroll
        for (int rr = 0; rr < 4; ++rr) {
          float v = acc[i][j][rr];
          ps += v;
          pq += v * v;
        }
      ps += __shfl_xor(ps, 16);
      ps += __shfl_xor(ps, 32);
      pq += __shfl_xor(pq, 16);
      pq += __shfl_xor(pq, 32);
      if (lane < 16) {
        atomicAdd(&st[col], ps);
        atomicAdd(&st[Nc + col], pq);
      }
    }
    // device-scope grid barrier (all blocks co-resident by construction)
    __syncthreads();  // drains this block's atomics (vmcnt 0) before signal
    if (t == 0) {
      __threadfence();
      __hip_atomic_fetch_add(cnt, 1u, __ATOMIC_ACQ_REL, __HIP_MEMORY_SCOPE_AGENT);
      while (__hip_atomic_load(cnt, __ATOMIC_ACQUIRE, __HIP_MEMORY_SCOPE_AGENT) <
             (unsigned)nblk) {
        __builtin_amdgcn_s_sleep(8);
      }
    }
    __syncthreads();
    // finalize + apply + single store
    const float inv = 1.0f / 12544.0f;
#pragma unroll
    for (int j = 0; j < NJ; ++j) {
      int col = n0 + wn * (BN / 2) + j * 16 + r;
      float s0 = __hip_atomic_load(&st[col], __ATOMIC_RELAXED, __HIP_MEMORY_SCOPE_AGENT);
      float q0 = __hip_atomic_load(&st[Nc + col], __ATOMIC_RELAXED, __HIP_MEMORY_SCOPE_AGENT);
      float mean_raw = s0 * inv;
      float var = q0 * inv - mean_raw * mean_raw;   // var(v+b) == var(v)
      float sc = gamma[col] * rsqrtf(var + 1e-5f);
      float sh = beta[col] - (mean_raw + bias[col]) * sc;
#pragma unroll
      for (int i = 0; i < MI; ++i) {
        int row_base = m0 + wm * (BM / 2) + i * 16 + g * 4;
#pragma unroll
        for (int rr = 0; rr < 4; ++rr) {
          float v = fmaxf(sc * acc[i][j][rr] + sh, 0.f);
          Yb[(size_t)(row_base + rr) * Nc + col] = f2bf(v);
        }
      }
    }
  }
}

// -------- final: out = relu(x + softplus(rs)*bn3(y3)); sc/sh in-kernel -------
__global__ __launch_bounds__(256) void k_final(const float* __restrict__ x,
                                               const short* __restrict__ y3b,
                                               const float* __restrict__ st,
                                               const float* __restrict__ gamma,
                                               const float* __restrict__ beta,
                                               const float* __restrict__ rs,
                                               float* __restrict__ out) {
  __shared__ short ytile[64][198];
  __shared__ float lsc[64], lsh[64];
  const int n = blockIdx.x;
  const int co0 = blockIdx.y * 64;
  const int t = threadIdx.x;
  if (t < 64) {
    const float inv = 1.0f / 12544.0f;
    int c = co0 + t;
    float mean = st[c] * inv;
    float var = st[1024 + c] * inv - mean * mean;
    float s = gamma[c] * rsqrtf(var + 1e-5f);
    lsc[t] = s;
    lsh[t] = beta[c] - mean * s;
  }
#pragma unroll
  for (int iter = 0; iter < 49; ++iter) {
    int idx = iter * 256 + t;
    int hw = idx >> 6, c = idx & 63;
    ytile[c][hw] = y3b[((size_t)(n * 196 + hw)) * 1024 + co0 + c];
  }
  __syncthreads();
  float z = rs[0];
  float s = fmaxf(z, 0.f) + log1pf(expf(-fabsf(z)));  // stable softplus
#pragma unroll
  for (int iter = 0; iter < 49; ++iter) {
    int idx = iter * 256 + t;
    int co = idx / 196, hw = idx - co * 196;
    size_t xi = ((size_t)(n * 1024 + co0 + co)) * 196 + hw;
    float v = bf2f(ytile[co][hw]);
    float o = x[xi] + s * (lsc[co] * v + lsh[co]);
    out[xi] = fmaxf(o, 0.f);
  }
}

extern "C" void kernel_launch(void* const* d_in, const int* in_sizes, int n_in,
                              void* d_out, int out_size, void* d_ws, size_t ws_size,
                              hipStream_t stream) {
  const float* x   = (const float*)d_in[0];
  const float* w1  = (const float*)d_in[1];
  const float* b1  = (const float*)d_in[2];
  const float* g1  = (const float*)d_in[3];
  const float* be1 = (const float*)d_in[4];
  const float* w2  = (const float*)d_in[5];
  const float* b2  = (const float*)d_in[6];
  const float* g2  = (const float*)d_in[7];
  const float* be2 = (const float*)d_in[8];
  const float* w3  = (const float*)d_in[9];
  const float* b3  = (const float*)d_in[10];
  const float* g3  = (const float*)d_in[11];
  const float* be3 = (const float*)d_in[12];
  const float* rs  = (const float*)d_in[13];
  float* out = (float*)d_out;
  char* ws = (char*)d_ws;

  size_t off = 0;
  auto alloc = [&](size_t bytes) {
    size_t o = off;
    off += (bytes + 255) & ~(size_t)255;
    return o;
  };
  short* xb  = (short*)(ws + alloc((size_t)MTOT * CIN * 2));
  short* w1b = (short*)(ws + alloc((size_t)262144 * 2));
  short* w2b = (short*)(ws + alloc((size_t)589824 * 2));
  short* w3b = (short*)(ws + alloc((size_t)262144 * 2));
  short* y1b = (short*)(ws + alloc((size_t)MTOT * PL * 2));
  short* y2b = (short*)(ws + alloc((size_t)MTOT * PL * 2));
  short* y3b = (short*)(ws + alloc((size_t)MTOT * COUT * 2));
  float* stats = (float*)(ws + alloc(3200 * 4));
  float* stat1 = stats, *stat2 = stats + 512, *stat3 = stats + 1024;
  unsigned* cnt1 = (unsigned*)(stats + 3072);
  unsigned* cnt2 = (unsigned*)(stats + 3073);
  short* zerobuf = (short*)(stats + 3136);  // 256B, zeroed by prep

  k_prep<<<6401, 256, 0, stream>>>(x, w1, w2, w3, xb, w1b, w2b, w3b, stats);

  // conv1: 1x1 reduce (K=1024 -> 256), 128x64 tiles, 392 blocks, fused BN
  gemm_kernel<0, 1024, 128, 64, 1><<<dim3(98, 4), 256, 0, stream>>>(
      xb, w1b, b1, g1, be1, y1b, stat1, cnt1, 392, 256, zerobuf);

  // conv2: 3x3 (K=2304 -> 256), 64x128 tiles, 392 blocks, fused BN
  gemm_kernel<1, 2304, 64, 128, 1><<<dim3(196, 2), 256, 0, stream>>>(
      y1b, w2b, b2, g2, be2, y2b, stat2, cnt2, 392, 256, zerobuf);

  // conv3: 1x1 expand (K=256 -> 1024), 128x128 tiles, 784 blocks, unfused
  gemm_kernel<0, 256, 128, 128, 0><<<dim3(98, 8), 256, 0, stream>>>(
      y2b, w3b, b3, g3, be3, y3b, stat3, nullptr, 0, 1024, zerobuf);

  // residual + relu (+ bn3 finalize in-kernel)
  k_final<<<dim3(64, 16), 256, 0, stream>>>(x, y3b, stat3, g3, be3, rs, out);
}

// Round 9
// 122.649 us; speedup vs baseline: 1.5063x; 1.5063x over previous
//
#include <hip/hip_runtime.h>
#include <hip/hip_bf16.h>
#include <cstdint>

#define NB   64
#define CIN  1024
#define HWSP 196
#define MTOT 12544
#define PL   256
#define COUT 1024

using f32x4 = __attribute__((ext_vector_type(4))) float;
using s16x8 = __attribute__((ext_vector_type(8))) short;

static __device__ __forceinline__ short f2bf(float f) {
  union { __hip_bfloat16 h; short s; } u;
  u.h = __float2bfloat16(f);
  return u.s;
}
static __device__ __forceinline__ float bf2f(short s) {
  union { float f; unsigned u; } x;
  x.u = ((unsigned)(unsigned short)s) << 16;
  return x.f;
}

static __device__ __forceinline__ void gload16(const void* g, void* l) {
  __builtin_amdgcn_global_load_lds((const __attribute__((address_space(1))) void*)g,
                                   (__attribute__((address_space(3))) void*)l, 16, 0, 0);
}

// ------------- merged prep: x-transpose | weight cast/reorder | stats zero ---
__global__ __launch_bounds__(256) void k_prep(const float* __restrict__ x,
                                              const float* __restrict__ w1,
                                              const float* __restrict__ w2,
                                              const float* __restrict__ w3,
                                              short* __restrict__ xb,
                                              short* __restrict__ w1b,
                                              short* __restrict__ w2b,
                                              short* __restrict__ w3b,
                                              float* __restrict__ statszero) {
  const int bid = blockIdx.x;
  if (bid < 2048) {
    __shared__ float tile[32][197];
    const int n = bid >> 5;
    const int c0 = (bid & 31) * 32;
    for (int idx = threadIdx.x; idx < 32 * 196; idx += 256) {
      int cl = idx / 196, hw = idx % 196;
      tile[cl][hw] = x[((size_t)(n * CIN + c0 + cl)) * HWSP + hw];
    }
    __syncthreads();
    for (int idx = threadIdx.x; idx < 196 * 32; idx += 256) {
      int hw = idx >> 5, cl = idx & 31;
      xb[((size_t)(n * HWSP + hw)) * CIN + c0 + cl] = f2bf(tile[cl][hw]);
    }
  } else if (bid < 6400) {
    int i = (bid - 2048) * 256 + threadIdx.x;
    if (i < 262144) w1b[i] = f2bf(w1[i]);
    int j = i - 262144;
    if (j >= 0 && j < 589824) {
      int co = j / 2304, rem = j % 2304;
      int d = rem >> 8, ci = rem & 255;
      w2b[j] = f2bf(w2[((size_t)(co * 256 + ci)) * 9 + d]);
    }
    int k = i - 851968;
    if (k >= 0 && k < 262144) w3b[k] = f2bf(w3[k]);
  } else {
    for (int k = threadIdx.x; k < 3136; k += 256) statszero[k] = 0.f;
  }
}

// ---------------- MFMA GEMM + fused bias + BN-stats epilogue -----------------
// Tile 128x128x64; 4 waves (2x2), per-wave 64x64, acc[4][4].
// Counted-vmcnt double buffer (T4): per K-tile
//   stage(next: 8 gloads) ; s_waitcnt vmcnt(8) [own tile-kt loads landed,
//   next-tile loads stay in flight] ; s_barrier ; compute(cur) ; s_barrier.
// No vmcnt(0) drain in the main loop; no sched_barrier pinning (m141).
// Post-compute barrier needs no drain: MFMA data-deps force lgkm waits, so
// all ds_reads have returned before any wave passes it (safe buffer reuse).
// LDS read swizzle: byte = row*128 + ((k16 ^ (row&7)) << 4); staging uses
// linear LDS dest + inverse-swizzled global source (rule #21).
static __device__ __forceinline__ int swz(int row, int k16) {
  return row * 128 + (((unsigned)(k16 ^ (row & 7))) << 4);
}

template <int MODE, int K>
__global__ __launch_bounds__(256) void gemm_kernel(const short* __restrict__ A,
                                                   const short* __restrict__ Bw,
                                                   const float* __restrict__ bias,
                                                   short* __restrict__ Yb,
                                                   float* __restrict__ st,
                                                   int Nc,
                                                   const short* __restrict__ zerobuf) {
  __shared__ __align__(16) char lds[2][32768];  // per buf: A 16KB | B 16KB

  const int m0 = blockIdx.x * 128;
  const int n0 = blockIdx.y * 128;
  const int t = threadIdx.x;
  const int lane = t & 63, wid = t >> 6;
  const int wm = wid >> 1, wn = wid & 1;
  const int g = lane >> 4, r = lane & 15;
  constexpr int NKT = K >> 6;

  const short* aSrc[4];
  int aN[4], aH[4], aW[4], aCi[4];
  const short* bSrc[4];
#pragma unroll
  for (int q = 0; q < 4; ++q) {
    int chunk = t + q * 256;
    int row = chunk >> 3;
    int k16s = (chunk & 7) ^ (row & 7);
    if (MODE == 0) {
      aSrc[q] = A + (size_t)(m0 + row) * K + k16s * 8;
    } else {
      int m = m0 + row;
      int n_ = m / 196;
      int hw = m - n_ * 196;
      aN[q] = n_;
      aH[q] = hw / 14;
      aW[q] = hw - aH[q] * 14;
      aCi[q] = k16s * 8;
    }
    bSrc[q] = Bw + (size_t)(n0 + row) * K + k16s * 8;
  }

  auto stage = [&](int buf, int kt) {
    const int k0 = kt << 6;
    char* dA = &lds[buf][0];
    char* dB = &lds[buf][16384];
#pragma unroll
    for (int q = 0; q < 4; ++q) {
      const short* s;
      if (MODE == 0) {
        s = aSrc[q] + k0;
      } else {
        int d = kt >> 2;
        int dh = d / 3, dw = d - dh * 3;
        int hh = aH[q] + dh - 1, ww = aW[q] + dw - 1;
        s = ((unsigned)hh < 14u && (unsigned)ww < 14u)
                ? A + ((size_t)(aN[q] * 196 + hh * 14 + ww)) * 256 + (k0 & 255) + aCi[q]
                : zerobuf;
      }
      gload16(s, dA + (t + q * 256) * 16);
    }
#pragma unroll
    for (int q = 0; q < 4; ++q)
      gload16(bSrc[q] + k0, dB + (t + q * 256) * 16);
  };

  f32x4 acc[4][4] = {};
  auto compute = [&](int buf) {
    char* baseA = &lds[buf][0];
    char* baseB = &lds[buf][16384];
#pragma unroll
    for (int ks = 0; ks < 2; ++ks) {
      s16x8 af[4], bfr[4];
#pragma unroll
      for (int i = 0; i < 4; ++i)
        af[i] = *(const s16x8*)(baseA + swz(wm * 64 + i * 16 + r, ks * 4 + g));
#pragma unroll
      for (int j = 0; j < 4; ++j)
        bfr[j] = *(const s16x8*)(baseB + swz(wn * 64 + j * 16 + r, ks * 4 + g));
#pragma unroll
      for (int i = 0; i < 4; ++i)
#pragma unroll
        for (int j = 0; j < 4; ++j)
          acc[i][j] = __builtin_amdgcn_mfma_f32_16x16x32_bf16(af[i], bfr[j], acc[i][j], 0, 0, 0);
    }
  };

  stage(0, 0);
  int cur = 0;
#pragma unroll 1
  for (int kt = 0; kt < NKT - 1; ++kt) {
    stage(cur ^ 1, kt + 1);                            // 8 loads in flight
    asm volatile("s_waitcnt vmcnt(8)" ::: "memory");   // tile kt landed
    __builtin_amdgcn_s_barrier();
    compute(cur);
    asm volatile("" ::: "memory");
    __builtin_amdgcn_s_barrier();                      // reads done; buf reusable
    cur ^= 1;
  }
  asm volatile("s_waitcnt vmcnt(0)" ::: "memory");
  __builtin_amdgcn_s_barrier();
  compute(cur);

  // epilogue: bias, bf16 store, per-channel sum/sumsq -> atomics
#pragma unroll
  for (int j = 0; j < 4; ++j) {
    int col = n0 + wn * 64 + j * 16 + r;
    float bv = bias[col];
    float ps = 0.f, pq = 0.f;
#pragma unroll
    for (int i = 0; i < 4; ++i) {
      int row_base = m0 + wm * 64 + i * 16 + g * 4;
#pragma unroll
      for (int rr = 0; rr < 4; ++rr) {
        float v = acc[i][j][rr] + bv;
        ps += v;
        pq += v * v;
        Yb[(size_t)(row_base + rr) * Nc + col] = f2bf(v);
      }
    }
    ps += __shfl_xor(ps, 16);
    ps += __shfl_xor(ps, 32);
    pq += __shfl_xor(pq, 16);
    pq += __shfl_xor(pq, 32);
    if (lane < 16) {
      atomicAdd(&st[col], ps);
      atomicAdd(&st[Nc + col], pq);
    }
  }
}

// ------- in-place: yb = bf16(relu(sc*yb+sh)), C=256; sc/sh computed here -----
__global__ __launch_bounds__(256) void k_apply(short* __restrict__ Yb,
                                               const float* __restrict__ st,
                                               const float* __restrict__ gamma,
                                               const float* __restrict__ beta) {
  __shared__ float lsc[256], lsh[256];
  const int t = threadIdx.x;
  {
    const float inv = 1.0f / 12544.0f;
    float mean = st[t] * inv;
    float var = st[256 + t] * inv - mean * mean;
    float s = gamma[t] * rsqrtf(var + 1e-5f);
    lsc[t] = s;
    lsh[t] = beta[t] - mean * s;
  }
  __syncthreads();
  size_t i8 = ((size_t)blockIdx.x * 256 + t) * 8;
  s16x8 v = *(const s16x8*)(Yb + i8);
  int c0 = (int)(i8 & 255);
#pragma unroll
  for (int e = 0; e < 8; ++e) {
    float f = bf2f(v[e]);
    v[e] = f2bf(fmaxf(lsc[c0 + e] * f + lsh[c0 + e], 0.f));
  }
  *(s16x8*)(Yb + i8) = v;
}

// -------- final: out = relu(x + softplus(rs)*bn3(y3)); sc/sh in-kernel -------
__global__ __launch_bounds__(256) void k_final(const float* __restrict__ x,
                                               const short* __restrict__ y3b,
                                               const float* __restrict__ st,
                                               const float* __restrict__ gamma,
                                               const float* __restrict__ beta,
                                               const float* __restrict__ rs,
                                               float* __restrict__ out) {
  __shared__ short ytile[64][198];
  __shared__ float lsc[64], lsh[64];
  const int n = blockIdx.x;
  const int co0 = blockIdx.y * 64;
  const int t = threadIdx.x;
  if (t < 64) {
    const float inv = 1.0f / 12544.0f;
    int c = co0 + t;
    float mean = st[c] * inv;
    float var = st[1024 + c] * inv - mean * mean;
    float s = gamma[c] * rsqrtf(var + 1e-5f);
    lsc[t] = s;
    lsh[t] = beta[c] - mean * s;
  }
#pragma unroll
  for (int iter = 0; iter < 49; ++iter) {
    int idx = iter * 256 + t;
    int hw = idx >> 6, c = idx & 63;
    ytile[c][hw] = y3b[((size_t)(n * 196 + hw)) * 1024 + co0 + c];
  }
  __syncthreads();
  float z = rs[0];
  float s = fmaxf(z, 0.f) + log1pf(expf(-fabsf(z)));  // stable softplus
#pragma unroll
  for (int iter = 0; iter < 49; ++iter) {
    int idx = iter * 256 + t;
    int co = idx / 196, hw = idx - co * 196;
    size_t xi = ((size_t)(n * 1024 + co0 + co)) * 196 + hw;
    float v = bf2f(ytile[co][hw]);
    float o = x[xi] + s * (lsc[co] * v + lsh[co]);
    out[xi] = fmaxf(o, 0.f);
  }
}

extern "C" void kernel_launch(void* const* d_in, const int* in_sizes, int n_in,
                              void* d_out, int out_size, void* d_ws, size_t ws_size,
                              hipStream_t stream) {
  const float* x   = (const float*)d_in[0];
  const float* w1  = (const float*)d_in[1];
  const float* b1  = (const float*)d_in[2];
  const float* g1  = (const float*)d_in[3];
  const float* be1 = (const float*)d_in[4];
  const float* w2  = (const float*)d_in[5];
  const float* b2  = (const float*)d_in[6];
  const float* g2  = (const float*)d_in[7];
  const float* be2 = (const float*)d_in[8];
  const float* w3  = (const float*)d_in[9];
  const float* b3  = (const float*)d_in[10];
  const float* g3  = (const float*)d_in[11];
  const float* be3 = (const float*)d_in[12];
  const float* rs  = (const float*)d_in[13];
  float* out = (float*)d_out;
  char* ws = (char*)d_ws;

  size_t off = 0;
  auto alloc = [&](size_t bytes) {
    size_t o = off;
    off += (bytes + 255) & ~(size_t)255;
    return o;
  };
  short* xb  = (short*)(ws + alloc((size_t)MTOT * CIN * 2));
  short* w1b = (short*)(ws + alloc((size_t)262144 * 2));
  short* w2b = (short*)(ws + alloc((size_t)589824 * 2));
  short* w3b = (short*)(ws + alloc((size_t)262144 * 2));
  short* y1b = (short*)(ws + alloc((size_t)MTOT * PL * 2));
  short* y2b = (short*)(ws + alloc((size_t)MTOT * PL * 2));
  short* y3b = (short*)(ws + alloc((size_t)MTOT * COUT * 2));
  float* stats = (float*)(ws + alloc(12288 + 256));
  float* stat1 = stats, *stat2 = stats + 512, *stat3 = stats + 1024;
  short* zerobuf = (short*)(stats + 3072);

  k_prep<<<6401, 256, 0, stream>>>(x, w1, w2, w3, xb, w1b, w2b, w3b, stats);

  // conv1: 1x1 reduce (K=1024 -> 256)
  gemm_kernel<0, 1024><<<dim3(98, 2), 256, 0, stream>>>(xb, w1b, b1, y1b, stat1, 256, zerobuf);
  k_apply<<<1568, 256, 0, stream>>>(y1b, stat1, g1, be1);

  // conv2: 3x3 (K=2304 -> 256)
  gemm_kernel<1, 2304><<<dim3(98, 2), 256, 0, stream>>>(y1b, w2b, b2, y2b, stat2, 256, zerobuf);
  k_apply<<<1568, 256, 0, stream>>>(y2b, stat2, g2, be2);

  // conv3: 1x1 expand (K=256 -> 1024)
  gemm_kernel<0, 256><<<dim3(98, 8), 256, 0, stream>>>(y2b, w3b, b3, y3b, stat3, 1024, zerobuf);

  // residual + relu (+ bn3 finalize in-kernel)
  k_final<<<dim3(64, 16), 256, 0, stream>>>(x, y3b, stat3, g3, be3, rs, out);
}